// Round 6
// baseline (656.043 us; speedup 1.0000x reference)
//
#include <hip/hip_runtime.h>
#include <stdint.h>
#include <math.h>

#define DEV static __device__ __forceinline__

typedef __attribute__((ext_vector_type(8))) short bf16x8;
typedef __attribute__((ext_vector_type(4))) float f32x4;

// ---------------- Threefry-2x32/20 (exact JAX schedule) ----------------
DEV uint32_t rotl32(uint32_t v, int d) { return (v << d) | (v >> (32 - d)); }

DEV void threefry2x32(uint32_t k0, uint32_t k1, uint32_t& x0, uint32_t& x1) {
  const uint32_t k2 = k0 ^ k1 ^ 0x1BD11BDAu;
  x0 += k0; x1 += k1;
#define TFR(R) { x0 += x1; x1 = rotl32(x1, R) ^ x0; }
  TFR(13) TFR(15) TFR(26) TFR(6)
  x0 += k1; x1 += k2 + 1u;
  TFR(17) TFR(29) TFR(16) TFR(24)
  x0 += k2; x1 += k0 + 2u;
  TFR(13) TFR(15) TFR(26) TFR(6)
  x0 += k0; x1 += k1 + 3u;
  TFR(17) TFR(29) TFR(16) TFR(24)
  x0 += k1; x1 += k2 + 4u;
  TFR(13) TFR(15) TFR(26) TFR(6)
  x0 += k2; x1 += k0 + 5u;
#undef TFR
}

// ---------------- erfinv (XLA f32 ErfInv, Giles 2012) ----------------
DEV float erfinv_f32(float x) {
  float w = -log1pf(-x * x);
  float p;
  if (w < 5.0f) {
    w -= 2.5f;
    p = 2.81022636e-08f;
    p = fmaf(p, w, 3.43273939e-07f);
    p = fmaf(p, w, -3.5233877e-06f);
    p = fmaf(p, w, -4.39150654e-06f);
    p = fmaf(p, w, 0.00021858087f);
    p = fmaf(p, w, -0.00125372503f);
    p = fmaf(p, w, -0.00417768164f);
    p = fmaf(p, w, 0.246640727f);
    p = fmaf(p, w, 1.50140941f);
  } else {
    w = sqrtf(w) - 3.0f;
    p = -0.000200214257f;
    p = fmaf(p, w, 0.000100950558f);
    p = fmaf(p, w, 0.00134934322f);
    p = fmaf(p, w, -0.00367342844f);
    p = fmaf(p, w, 0.00573950773f);
    p = fmaf(p, w, -0.0076224613f);
    p = fmaf(p, w, 0.00943887047f);
    p = fmaf(p, w, 1.00167406f);
    p = fmaf(p, w, 2.83297682f);
  }
  return p * x;
}

DEV float normal_from_bits(uint32_t bits) {
  float f = __uint_as_float((bits >> 9) | 0x3F800000u) - 1.0f;
  const float lo = -0.99999994f;            // nextafter(-1, 0) in f32
  float u = fmaf(f, 2.0f, lo);
  u = fmaxf(u, lo);
  return 1.41421356f * erfinv_f32(u);
}

DEV unsigned short f2bf(float f) {   // RTNE f32 -> bf16
  uint32_t u = __float_as_uint(f);
  uint32_t r = u + 0x7FFFu + ((u >> 16) & 1u);
  return (unsigned short)(r >> 16);
}

DEV float bf2f(uint32_t h) { return __uint_as_float(h << 16); }

// ---------------- CSR build ----------------
__global__ void count_kernel(const int* __restrict__ rows, const int* __restrict__ cols,
                             int* __restrict__ counts, int* __restrict__ degs, int E) {
  int e = blockIdx.x * blockDim.x + threadIdx.x;
  if (e < E) {
    int r = rows[e];
    atomicAdd(&counts[r], 1);
    if (r != cols[e]) atomicAdd(&degs[r], 1);
  }
}

__global__ void dinv_kernel(const int* __restrict__ degs, float* __restrict__ dinv, int N) {
  int i = blockIdx.x * blockDim.x + threadIdx.x;
  if (i < N) {
    int d = degs[i];
    dinv[i] = d > 0 ? rsqrtf((float)d) : 0.0f;
  }
}

#define SCAN_T 1024
__global__ __launch_bounds__(SCAN_T) void scan_kernel(const int* __restrict__ counts,
                                                      int* __restrict__ row_ptr,
                                                      int* __restrict__ cursor, int N) {
  __shared__ int sa[SCAN_T], sb[SCAN_T];
  const int t = threadIdx.x;
  const int CH = (N + SCAN_T - 1) / SCAN_T;
  int base = t * CH;
  int psum = 0;
  for (int k = 0; k < CH; ++k) {
    int idx = base + k;
    if (idx < N) psum += counts[idx];
  }
  sa[t] = psum;
  __syncthreads();
  int* src = sa; int* dst = sb;
  for (int off = 1; off < SCAN_T; off <<= 1) {
    int v = src[t];
    if (t >= off) v += src[t - off];
    dst[t] = v;
    __syncthreads();
    int* tmp = src; src = dst; dst = tmp;
  }
  int running = src[t] - psum;
  for (int k = 0; k < CH; ++k) {
    int idx = base + k;
    if (idx < N) {
      row_ptr[idx] = running;
      cursor[idx] = running;
      running += counts[idx];
    }
  }
  if (t == SCAN_T - 1) row_ptr[N] = running;
}

__global__ void fill_kernel(const int* __restrict__ rows, const int* __restrict__ cols,
                            const float* __restrict__ dinv, int* __restrict__ cursor,
                            float2* __restrict__ ecv, int E) {
  int e = blockIdx.x * blockDim.x + threadIdx.x;
  if (e < E) {
    int r = rows[e], c = cols[e];
    float w = (r != c) ? -dinv[r] * dinv[c] : 0.0f;
    int pos = atomicAdd(&cursor[r], 1);
    ecv[pos] = make_float2(__int_as_float(c), w);
  }
}

// ---------------- row loader: VEC floats from f32 or bf16 source ----------------
template <int VEC, int BSRC>
DEV void ldrow(const void* base, size_t off, float* v) {
  if (BSRC) {
    const unsigned short* p = (const unsigned short*)base + off;
    if (VEC == 4) {
      uint2 u = *(const uint2*)p;
      v[0] = bf2f(u.x & 0xffffu); v[1] = bf2f(u.x >> 16);
      v[2] = bf2f(u.y & 0xffffu); v[3] = bf2f(u.y >> 16);
    } else {
      uint32_t u = *(const uint32_t*)p;
      v[0] = bf2f(u & 0xffffu); v[1] = bf2f(u >> 16);
    }
  } else {
    const float* p = (const float*)base + off;
    if (VEC == 4) {
      float4 t = *(const float4*)p;
      v[0] = t.x; v[1] = t.y; v[2] = t.z; v[3] = t.w;
    } else {
      float2 t = *(const float2*)p;
      v[0] = t.x; v[1] = t.y;
    }
  }
}

// ---------------- propagation: one wave per node, 4-edge unrolled gather ----------------
// SUB=0: outb = bf16(P x)
// SUB=1: outb = bf16(2*P x - xsub)
template <int VEC, int SUB, int BSRC>
__global__ __launch_bounds__(256) void gather_prop(
    const int* __restrict__ row_ptr, const float2* __restrict__ ecv,
    const void* __restrict__ xsrc, int sstride,
    const float* __restrict__ xsub, int substride,
    unsigned short* __restrict__ outb, int N, int F, int Fpad) {
  const int wave = threadIdx.x >> 6, lane = threadIdx.x & 63;
  const int node = blockIdx.x * 4 + wave;
  if (node >= N) return;
  const int f0 = lane * VEC;
  if (f0 >= Fpad) return;
  const bool live = (f0 + VEC) <= F;
  float acc[VEC] = {};
  if (live) {
    const int s = row_ptr[node], e = row_ptr[node + 1];
    int j = s;
    for (; j + 4 <= e; j += 4) {
      float2 c0 = ecv[j], c1 = ecv[j + 1], c2 = ecv[j + 2], c3 = ecv[j + 3];
      float v0[VEC], v1[VEC], v2[VEC], v3[VEC];
      ldrow<VEC, BSRC>(xsrc, (size_t)__float_as_int(c0.x) * sstride + f0, v0);
      ldrow<VEC, BSRC>(xsrc, (size_t)__float_as_int(c1.x) * sstride + f0, v1);
      ldrow<VEC, BSRC>(xsrc, (size_t)__float_as_int(c2.x) * sstride + f0, v2);
      ldrow<VEC, BSRC>(xsrc, (size_t)__float_as_int(c3.x) * sstride + f0, v3);
#pragma unroll
      for (int q = 0; q < VEC; ++q) {
        acc[q] = fmaf(c0.y, v0[q], acc[q]);
        acc[q] = fmaf(c1.y, v1[q], acc[q]);
        acc[q] = fmaf(c2.y, v2[q], acc[q]);
        acc[q] = fmaf(c3.y, v3[q], acc[q]);
      }
    }
    for (; j < e; ++j) {
      float2 cw = ecv[j];
      float vv[VEC];
      ldrow<VEC, BSRC>(xsrc, (size_t)__float_as_int(cw.x) * sstride + f0, vv);
#pragma unroll
      for (int q = 0; q < VEC; ++q) acc[q] = fmaf(cw.y, vv[q], acc[q]);
    }
    if (SUB) {
      const float* sb = xsub + (size_t)node * substride + f0;
#pragma unroll
      for (int q = 0; q < VEC; ++q) acc[q] = fmaf(2.0f, acc[q], -sb[q]);
    }
  }
  size_t ob = (size_t)node * Fpad + f0;
  if (VEC == 4) {
    uint2 u;
    u.x = (uint32_t)f2bf(acc[0]) | ((uint32_t)f2bf(acc[1]) << 16);
    u.y = (uint32_t)f2bf(acc[2]) | ((uint32_t)f2bf(acc[3]) << 16);
    *(uint2*)&outb[ob] = u;
  } else {
    uint32_t u = (uint32_t)f2bf(acc[0]) | ((uint32_t)f2bf(acc[1]) << 16);
    *(uint32_t*)&outb[ob] = u;
  }
}

// ---------------- weight transpose+convert: Wt[p][o][k] = bf16(W[p][k][o]) ----------------
__global__ void wtrans_kernel(const float* __restrict__ W, unsigned short* __restrict__ Wt,
                              int F, int Fpad, int O) {
  int idx = blockIdx.x * 256 + threadIdx.x;
  int total = 3 * O * Fpad;
  if (idx >= total) return;
  int k = idx % Fpad;
  int o = (idx / Fpad) % O;
  int p = idx / (Fpad * O);
  Wt[idx] = (k < F) ? f2bf(W[((size_t)p * F + k) * O + o]) : (unsigned short)0;
}

// ---------------- input convert: vb[i][k<96] = bf16(v[i][k<86]) ----------------
__global__ void vconv_kernel(const float* __restrict__ v, unsigned short* __restrict__ vb, int N) {
  int i = blockIdx.x * 256 + threadIdx.x;
  if (i >= N * 96) return;
  int r = i / 96, k = i % 96;
  vb[i] = (k < 86) ? f2bf(v[(size_t)r * 86 + k]) : (unsigned short)0;
}

// ---------------- LDS-free MFMA GEMM: out = relu(A0@W0+A1@W1+A2@W2+b)*noise ----------------
// 256 threads = 4 waves; wave tile 64 rows x (NO16*16) cols; all frags global->reg.
template <int NO16, int FPAD>
__global__ __launch_bounds__(256) void gemm3_mfma(
    const unsigned short* __restrict__ A0, const unsigned short* __restrict__ A1,
    const unsigned short* __restrict__ A2,
    const unsigned short* __restrict__ Wt, const float* __restrict__ bias,
    int M, int O, float* __restrict__ out, unsigned short* __restrict__ outb,
    int obstride, int fold) {
  const int lane = threadIdx.x & 63;
  const int wave = threadIdx.x >> 6;
  const int bm = blockIdx.x * 64;
  const int co = (blockIdx.y * 4 + wave) * (NO16 * 16);
  const int l15 = lane & 15;
  const int kg = (lane >> 4) * 8;

  f32x4 acc[4][NO16] = {};

  size_t aoff[4];
#pragma unroll
  for (int mi = 0; mi < 4; ++mi) {
    int r = bm + mi * 16 + l15;
    if (r >= M) r = M - 1;           // clamp tail rows; store is guarded
    aoff[mi] = (size_t)r * FPAD + kg;
  }
  size_t boff[NO16];
#pragma unroll
  for (int ni = 0; ni < NO16; ++ni)
    boff[ni] = (size_t)(co + ni * 16 + l15) * FPAD + kg;

  const unsigned short* As[3] = {A0, A1, A2};
#pragma unroll
  for (int p = 0; p < 3; ++p) {
    const unsigned short* __restrict__ A = As[p];
    const unsigned short* __restrict__ B = Wt + (size_t)p * O * FPAD;
#pragma unroll
    for (int k0 = 0; k0 < FPAD; k0 += 32) {
      bf16x8 af[4], bfr[NO16];
#pragma unroll
      for (int mi = 0; mi < 4; ++mi)
        af[mi] = *(const bf16x8*)(A + aoff[mi] + k0);
#pragma unroll
      for (int ni = 0; ni < NO16; ++ni)
        bfr[ni] = *(const bf16x8*)(B + boff[ni] + k0);
#pragma unroll
      for (int mi = 0; mi < 4; ++mi)
#pragma unroll
        for (int ni = 0; ni < NO16; ++ni)
          acc[mi][ni] = __builtin_amdgcn_mfma_f32_16x16x32_bf16(af[mi], bfr[ni], acc[mi][ni], 0, 0, 0);
    }
  }

  // epilogue: bias + relu + threefry noise (+ bf16 shadow for next layer)
  uint32_t f0 = 0u, f1 = (uint32_t)fold;
  threefry2x32(0u, 42u, f0, f1);
  const int r0 = (lane >> 4) * 4;
#pragma unroll
  for (int mi = 0; mi < 4; ++mi) {
#pragma unroll
    for (int r = 0; r < 4; ++r) {
      int gm = bm + mi * 16 + r0 + r;
      if (gm >= M) continue;
#pragma unroll
      for (int ni = 0; ni < NO16; ++ni) {
        int go = co + ni * 16 + l15;
        float vv = acc[mi][ni][r] + bias[go];
        vv = vv > 0.0f ? vv : 0.0f;
        uint32_t a = 0u, b = (uint32_t)(gm * O + go);
        threefry2x32(f0, f1, a, b);
        float res = vv * normal_from_bits(a ^ b);
        out[(size_t)gm * O + go] = res;
        if (outb) outb[(size_t)gm * obstride + go] = f2bf(res);
      }
    }
  }
}

// ---------------- host orchestration ----------------
extern "C" void kernel_launch(void* const* d_in, const int* in_sizes, int n_in,
                              void* d_out, int out_size, void* d_ws, size_t ws_size,
                              hipStream_t stream) {
  const float* v    = (const float*)d_in[0];
  const int*  edges = (const int*)d_in[1];
  const float* W1 = (const float*)d_in[2];
  const float* b1 = (const float*)d_in[3];
  const float* W2 = (const float*)d_in[4];
  const float* b2 = (const float*)d_in[5];
  const float* W3 = (const float*)d_in[6];
  const float* b3 = (const float*)d_in[7];
  float* out = (float*)d_out;

  const int N = in_sizes[0] / 86;
  const int E = in_sizes[1] / 2;
  const int* rows = edges;
  const int* cols = edges + E;

  // ---- ws carve (16B-aligned chunks) ----
  uintptr_t cur = (uintptr_t)d_ws;
  auto alloc = [&](size_t bytes) {
    cur = (cur + 15) & ~(uintptr_t)15;
    void* p = (void*)cur;
    cur += bytes;
    return p;
  };
  float2* ecv          = (float2*)alloc((size_t)E * 8);
  int* counts          = (int*)alloc((size_t)N * 4);
  int* degs            = (int*)alloc((size_t)N * 4);
  int* row_ptr         = (int*)alloc((size_t)(N + 1) * 4);
  int* cursor          = (int*)alloc((size_t)N * 4);
  float* dinv          = (float*)alloc((size_t)N * 4);
  unsigned short* tx1b = (unsigned short*)alloc((size_t)N * 256 * 2);
  unsigned short* tx2b = (unsigned short*)alloc((size_t)N * 256 * 2);
  unsigned short* vb   = (unsigned short*)alloc((size_t)N * 96 * 2);
  unsigned short* x1b  = (unsigned short*)alloc((size_t)N * 128 * 2);
  unsigned short* x2b  = (unsigned short*)alloc((size_t)N * 256 * 2);
  unsigned short* Wt   = (unsigned short*)alloc((size_t)3 * 512 * 256 * 2);

  float* x1 = out;
  float* x2 = x1 + (size_t)N * 128;
  float* x3 = x2 + (size_t)N * 256;

  // CSR build + norm
  hipMemsetAsync(counts, 0, (size_t)2 * N * sizeof(int), stream);
  count_kernel<<<(E + 255) / 256, 256, 0, stream>>>(rows, cols, counts, degs, E);
  dinv_kernel<<<(N + 255) / 256, 256, 0, stream>>>(degs, dinv, N);
  scan_kernel<<<1, SCAN_T, 0, stream>>>(counts, row_ptr, cursor, N);
  fill_kernel<<<(E + 255) / 256, 256, 0, stream>>>(rows, cols, dinv, cursor, ecv, E);
  vconv_kernel<<<(N * 96 + 255) / 256, 256, 0, stream>>>(v, vb, N);

  const int pblocks = (N + 3) / 4;
  const int mtiles = (N + 63) / 64;

  // ---- layer 1: F=86 (pad 96), O=128 ----
  {
    wtrans_kernel<<<(3 * 128 * 96 + 255) / 256, 256, 0, stream>>>(W1, Wt, 86, 96, 128);
    gather_prop<2, 0, 0><<<pblocks, 256, 0, stream>>>(row_ptr, ecv, v, 86, nullptr, 0, tx1b, N, 86, 96);
    gather_prop<2, 1, 1><<<pblocks, 256, 0, stream>>>(row_ptr, ecv, tx1b, 96, v, 86, tx2b, N, 86, 96);
    dim3 g(mtiles, 1);
    gemm3_mfma<2, 96><<<g, 256, 0, stream>>>(vb, tx1b, tx2b, Wt, b1, N, 128, x1, x1b, 128, 1);
  }
  // ---- layer 2: F=128, O=256 ----
  {
    wtrans_kernel<<<(3 * 256 * 128 + 255) / 256, 256, 0, stream>>>(W2, Wt, 128, 128, 256);
    gather_prop<2, 0, 0><<<pblocks, 256, 0, stream>>>(row_ptr, ecv, x1, 128, nullptr, 0, tx1b, N, 128, 128);
    gather_prop<2, 1, 1><<<pblocks, 256, 0, stream>>>(row_ptr, ecv, tx1b, 128, x1, 128, tx2b, N, 128, 128);
    dim3 g(mtiles, 1);
    gemm3_mfma<4, 128><<<g, 256, 0, stream>>>(x1b, tx1b, tx2b, Wt, b2, N, 256, x2, x2b, 256, 2);
  }
  // ---- layer 3: F=256, O=512 ----
  {
    wtrans_kernel<<<(3 * 512 * 256 + 255) / 256, 256, 0, stream>>>(W3, Wt, 256, 256, 512);
    gather_prop<4, 0, 0><<<pblocks, 256, 0, stream>>>(row_ptr, ecv, x2, 256, nullptr, 0, tx1b, N, 256, 256);
    gather_prop<4, 1, 1><<<pblocks, 256, 0, stream>>>(row_ptr, ecv, tx1b, 256, x2, 256, tx2b, N, 256, 256);
    dim3 g(mtiles, 2);
    gemm3_mfma<4, 256><<<g, 256, 0, stream>>>(x2b, tx1b, tx2b, Wt, b3, N, 512, x3, nullptr, 0, 3);
  }
}

// Round 7
// 401.900 us; speedup vs baseline: 1.6324x; 1.6324x over previous
//
#include <hip/hip_runtime.h>
#include <stdint.h>
#include <math.h>

#define DEV static __device__ __forceinline__

typedef __attribute__((ext_vector_type(8))) short bf16x8;
typedef __attribute__((ext_vector_type(4))) float f32x4;
typedef __attribute__((ext_vector_type(8))) unsigned short u16x8;

// ---------------- Threefry-2x32/20 (exact JAX schedule) ----------------
DEV uint32_t rotl32(uint32_t v, int d) { return (v << d) | (v >> (32 - d)); }

DEV void threefry2x32(uint32_t k0, uint32_t k1, uint32_t& x0, uint32_t& x1) {
  const uint32_t k2 = k0 ^ k1 ^ 0x1BD11BDAu;
  x0 += k0; x1 += k1;
#define TFR(R) { x0 += x1; x1 = rotl32(x1, R) ^ x0; }
  TFR(13) TFR(15) TFR(26) TFR(6)
  x0 += k1; x1 += k2 + 1u;
  TFR(17) TFR(29) TFR(16) TFR(24)
  x0 += k2; x1 += k0 + 2u;
  TFR(13) TFR(15) TFR(26) TFR(6)
  x0 += k0; x1 += k1 + 3u;
  TFR(17) TFR(29) TFR(16) TFR(24)
  x0 += k1; x1 += k2 + 4u;
  TFR(13) TFR(15) TFR(26) TFR(6)
  x0 += k2; x1 += k0 + 5u;
#undef TFR
}

// ---------------- erfinv (XLA f32 ErfInv, Giles 2012) ----------------
DEV float erfinv_f32(float x) {
  float w = -log1pf(-x * x);
  float p;
  if (w < 5.0f) {
    w -= 2.5f;
    p = 2.81022636e-08f;
    p = fmaf(p, w, 3.43273939e-07f);
    p = fmaf(p, w, -3.5233877e-06f);
    p = fmaf(p, w, -4.39150654e-06f);
    p = fmaf(p, w, 0.00021858087f);
    p = fmaf(p, w, -0.00125372503f);
    p = fmaf(p, w, -0.00417768164f);
    p = fmaf(p, w, 0.246640727f);
    p = fmaf(p, w, 1.50140941f);
  } else {
    w = sqrtf(w) - 3.0f;
    p = -0.000200214257f;
    p = fmaf(p, w, 0.000100950558f);
    p = fmaf(p, w, 0.00134934322f);
    p = fmaf(p, w, -0.00367342844f);
    p = fmaf(p, w, 0.00573950773f);
    p = fmaf(p, w, -0.0076224613f);
    p = fmaf(p, w, 0.00943887047f);
    p = fmaf(p, w, 1.00167406f);
    p = fmaf(p, w, 2.83297682f);
  }
  return p * x;
}

DEV float normal_from_bits(uint32_t bits) {
  float f = __uint_as_float((bits >> 9) | 0x3F800000u) - 1.0f;
  const float lo = -0.99999994f;            // nextafter(-1, 0) in f32
  float u = fmaf(f, 2.0f, lo);
  u = fmaxf(u, lo);
  return 1.41421356f * erfinv_f32(u);
}

DEV unsigned short f2bf(float f) {   // RTNE f32 -> bf16
  uint32_t u = __float_as_uint(f);
  uint32_t r = u + 0x7FFFu + ((u >> 16) & 1u);
  return (unsigned short)(r >> 16);
}

DEV float bf2f(uint32_t h) { return __uint_as_float(h << 16); }

// ---------------- CSR build ----------------
__global__ void count_kernel(const int* __restrict__ rows, const int* __restrict__ cols,
                             int* __restrict__ counts, int* __restrict__ degs, int E) {
  int e = blockIdx.x * blockDim.x + threadIdx.x;
  if (e < E) {
    int r = rows[e];
    atomicAdd(&counts[r], 1);
    if (r != cols[e]) atomicAdd(&degs[r], 1);
  }
}

__global__ void dinv_kernel(const int* __restrict__ degs, float* __restrict__ dinv, int N) {
  int i = blockIdx.x * blockDim.x + threadIdx.x;
  if (i < N) {
    int d = degs[i];
    dinv[i] = d > 0 ? rsqrtf((float)d) : 0.0f;
  }
}

#define SCAN_T 1024
__global__ __launch_bounds__(SCAN_T) void scan_kernel(const int* __restrict__ counts,
                                                      int* __restrict__ row_ptr,
                                                      int* __restrict__ cursor, int N) {
  __shared__ int sa[SCAN_T], sb[SCAN_T];
  const int t = threadIdx.x;
  const int CH = (N + SCAN_T - 1) / SCAN_T;
  int base = t * CH;
  int psum = 0;
  for (int k = 0; k < CH; ++k) {
    int idx = base + k;
    if (idx < N) psum += counts[idx];
  }
  sa[t] = psum;
  __syncthreads();
  int* src = sa; int* dst = sb;
  for (int off = 1; off < SCAN_T; off <<= 1) {
    int v = src[t];
    if (t >= off) v += src[t - off];
    dst[t] = v;
    __syncthreads();
    int* tmp = src; src = dst; dst = tmp;
  }
  int running = src[t] - psum;
  for (int k = 0; k < CH; ++k) {
    int idx = base + k;
    if (idx < N) {
      row_ptr[idx] = running;
      cursor[idx] = running;
      running += counts[idx];
    }
  }
  if (t == SCAN_T - 1) row_ptr[N] = running;
}

__global__ void fill_kernel(const int* __restrict__ rows, const int* __restrict__ cols,
                            const float* __restrict__ dinv, int* __restrict__ cursor,
                            float2* __restrict__ ecv, int E) {
  int e = blockIdx.x * blockDim.x + threadIdx.x;
  if (e < E) {
    int r = rows[e], c = cols[e];
    float w = (r != c) ? -dinv[r] * dinv[c] : 0.0f;
    int pos = atomicAdd(&cursor[r], 1);
    ecv[pos] = make_float2(__int_as_float(c), w);
  }
}

// ---------------- row loader: VEC floats from f32 or bf16 source ----------------
template <int VEC, int BSRC>
DEV void ldrow(const void* base, size_t off, float* v) {
  if (BSRC) {
    const unsigned short* p = (const unsigned short*)base + off;
    if (VEC == 4) {
      uint2 u = *(const uint2*)p;
      v[0] = bf2f(u.x & 0xffffu); v[1] = bf2f(u.x >> 16);
      v[2] = bf2f(u.y & 0xffffu); v[3] = bf2f(u.y >> 16);
    } else {
      uint32_t u = *(const uint32_t*)p;
      v[0] = bf2f(u & 0xffffu); v[1] = bf2f(u >> 16);
    }
  } else {
    const float* p = (const float*)base + off;
    if (VEC == 4) {
      float4 t = *(const float4*)p;
      v[0] = t.x; v[1] = t.y; v[2] = t.z; v[3] = t.w;
    } else {
      float2 t = *(const float2*)p;
      v[0] = t.x; v[1] = t.y;
    }
  }
}

// ---------------- propagation: one wave per node, 4-edge unrolled gather ----------------
// SUB=0: outb = bf16(P x)
// SUB=1: outb = bf16(2*P x - xsub)
template <int VEC, int SUB, int BSRC>
__global__ __launch_bounds__(256) void gather_prop(
    const int* __restrict__ row_ptr, const float2* __restrict__ ecv,
    const void* __restrict__ xsrc, int sstride,
    const float* __restrict__ xsub, int substride,
    unsigned short* __restrict__ outb, int N, int F, int Fpad) {
  const int wave = threadIdx.x >> 6, lane = threadIdx.x & 63;
  const int node = blockIdx.x * 4 + wave;
  if (node >= N) return;
  const int f0 = lane * VEC;
  if (f0 >= Fpad) return;
  const bool live = (f0 + VEC) <= F;
  float acc[VEC] = {};
  if (live) {
    const int s = row_ptr[node], e = row_ptr[node + 1];
    int j = s;
    for (; j + 4 <= e; j += 4) {
      float2 c0 = ecv[j], c1 = ecv[j + 1], c2 = ecv[j + 2], c3 = ecv[j + 3];
      float v0[VEC], v1[VEC], v2[VEC], v3[VEC];
      ldrow<VEC, BSRC>(xsrc, (size_t)__float_as_int(c0.x) * sstride + f0, v0);
      ldrow<VEC, BSRC>(xsrc, (size_t)__float_as_int(c1.x) * sstride + f0, v1);
      ldrow<VEC, BSRC>(xsrc, (size_t)__float_as_int(c2.x) * sstride + f0, v2);
      ldrow<VEC, BSRC>(xsrc, (size_t)__float_as_int(c3.x) * sstride + f0, v3);
#pragma unroll
      for (int q = 0; q < VEC; ++q) {
        acc[q] = fmaf(c0.y, v0[q], acc[q]);
        acc[q] = fmaf(c1.y, v1[q], acc[q]);
        acc[q] = fmaf(c2.y, v2[q], acc[q]);
        acc[q] = fmaf(c3.y, v3[q], acc[q]);
      }
    }
    for (; j < e; ++j) {
      float2 cw = ecv[j];
      float vv[VEC];
      ldrow<VEC, BSRC>(xsrc, (size_t)__float_as_int(cw.x) * sstride + f0, vv);
#pragma unroll
      for (int q = 0; q < VEC; ++q) acc[q] = fmaf(cw.y, vv[q], acc[q]);
    }
    if (SUB) {
      const float* sb = xsub + (size_t)node * substride + f0;
#pragma unroll
      for (int q = 0; q < VEC; ++q) acc[q] = fmaf(2.0f, acc[q], -sb[q]);
    }
  }
  size_t ob = (size_t)node * Fpad + f0;
  if (VEC == 4) {
    uint2 u;
    u.x = (uint32_t)f2bf(acc[0]) | ((uint32_t)f2bf(acc[1]) << 16);
    u.y = (uint32_t)f2bf(acc[2]) | ((uint32_t)f2bf(acc[3]) << 16);
    *(uint2*)&outb[ob] = u;
  } else {
    uint32_t u = (uint32_t)f2bf(acc[0]) | ((uint32_t)f2bf(acc[1]) << 16);
    *(uint32_t*)&outb[ob] = u;
  }
}

// ---------------- weight transpose+convert: Wt[p][o][k] = bf16(W[p][k][o]) ----------------
__global__ void wtrans_kernel(const float* __restrict__ W, unsigned short* __restrict__ Wt,
                              int F, int Fpad, int O) {
  int idx = blockIdx.x * 256 + threadIdx.x;
  int total = 3 * O * Fpad;
  if (idx >= total) return;
  int k = idx % Fpad;
  int o = (idx / Fpad) % O;
  int p = idx / (Fpad * O);
  Wt[idx] = (k < F) ? f2bf(W[((size_t)p * F + k) * O + o]) : (unsigned short)0;
}

// ---------------- input convert: vb[i][k<96] = bf16(v[i][k<86]) ----------------
__global__ void vconv_kernel(const float* __restrict__ v, unsigned short* __restrict__ vb, int N) {
  int i = blockIdx.x * 256 + threadIdx.x;
  if (i >= N * 96) return;
  int r = i / 96, k = i % 96;
  vb[i] = (k < 86) ? f2bf(v[(size_t)r * 86 + k]) : (unsigned short)0;
}

// ---------------- LDS-staged MFMA GEMM: out = relu(A0@W0+A1@W1+A2@W2+b)*noise ----------------
// 512 threads = 8 waves (2M x 4O); block tile BM x 128; K-step KS; all-bf16 staging.
template <int BM, int FPAD, int KS>
__global__ __launch_bounds__(512, 4) void gemm3_lds(
    const unsigned short* __restrict__ A0, const unsigned short* __restrict__ A1,
    const unsigned short* __restrict__ A2,
    const unsigned short* __restrict__ Wt, const float* __restrict__ bias,
    int M, int O, float* __restrict__ out, unsigned short* __restrict__ outb,
    int obstride, int fold) {
  constexpr int BN = 128;
  constexpr int CPR = KS / 8;           // u16x8 chunks per row
  constexpr int LST = KS + 8;           // LDS row stride (u16): +16B pad
  constexpr int NA = BM * CPR;
  constexpr int NB = BN * CPR;
  constexpr int ACH = (NA + 511) / 512;
  constexpr int BCH = (NB + 511) / 512;
  constexpr int MFR = BM / 32;          // m-frags per wave (wave covers BM/2 rows)
  constexpr int KK = KS / 32;

  __shared__ unsigned short sA[BM * LST];
  __shared__ unsigned short sB[BN * LST];

  const int tid = threadIdx.x;
  const int lane = tid & 63;
  const int wave = tid >> 6;
  const int wm = wave >> 2, wo = wave & 3;
  const int bm = blockIdx.x * BM;
  const int bo = blockIdx.y * BN;
  const int l15 = lane & 15;
  const int kg = (lane >> 4) * 8;

  f32x4 acc[MFR][2] = {};
  const unsigned short* As[3] = {A0, A1, A2};

#pragma unroll
  for (int p = 0; p < 3; ++p) {
    const unsigned short* __restrict__ A = As[p];
    const unsigned short* __restrict__ B = Wt + (size_t)p * O * FPAD;
    for (int k0 = 0; k0 < FPAD; k0 += KS) {
      // 1. issue global loads into regs (overlaps previous MFMA phase)
      u16x8 ra[ACH], rb[BCH];
#pragma unroll
      for (int c = 0; c < ACH; ++c) {
        int idx = tid + c * 512;
        if (NA % 512 == 0 || idx < NA) {
          int row = idx / CPR, ch = (idx % CPR) * 8;
          int gm = bm + row; if (gm >= M) gm = M - 1;   // clamp; stores guarded
          ra[c] = *(const u16x8*)(A + (size_t)gm * FPAD + k0 + ch);
        }
      }
#pragma unroll
      for (int c = 0; c < BCH; ++c) {
        int idx = tid + c * 512;
        if (NB % 512 == 0 || idx < NB) {
          int row = idx / CPR, ch = (idx % CPR) * 8;
          rb[c] = *(const u16x8*)(B + (size_t)(bo + row) * FPAD + k0 + ch);
        }
      }
      __syncthreads();
      // 2. LDS writes
#pragma unroll
      for (int c = 0; c < ACH; ++c) {
        int idx = tid + c * 512;
        if (NA % 512 == 0 || idx < NA) {
          int row = idx / CPR, ch = (idx % CPR) * 8;
          *(u16x8*)&sA[row * LST + ch] = ra[c];
        }
      }
#pragma unroll
      for (int c = 0; c < BCH; ++c) {
        int idx = tid + c * 512;
        if (NB % 512 == 0 || idx < NB) {
          int row = idx / CPR, ch = (idx % CPR) * 8;
          *(u16x8*)&sB[row * LST + ch] = rb[c];
        }
      }
      __syncthreads();
      // 3. fragments + MFMA
#pragma unroll
      for (int kk = 0; kk < KK; ++kk) {
        bf16x8 af[MFR], bfr[2];
#pragma unroll
        for (int mi = 0; mi < MFR; ++mi)
          af[mi] = *(const bf16x8*)&sA[(wm * (BM / 2) + mi * 16 + l15) * LST + kk * 32 + kg];
#pragma unroll
        for (int ni = 0; ni < 2; ++ni)
          bfr[ni] = *(const bf16x8*)&sB[(wo * 32 + ni * 16 + l15) * LST + kk * 32 + kg];
#pragma unroll
        for (int mi = 0; mi < MFR; ++mi)
#pragma unroll
          for (int ni = 0; ni < 2; ++ni)
            acc[mi][ni] = __builtin_amdgcn_mfma_f32_16x16x32_bf16(af[mi], bfr[ni], acc[mi][ni], 0, 0, 0);
      }
    }
  }

  // epilogue: bias + relu + threefry noise (+ bf16 shadow for next layer)
  uint32_t f0 = 0u, f1 = (uint32_t)fold;
  threefry2x32(0u, 42u, f0, f1);
  const int r0 = (lane >> 4) * 4;
#pragma unroll
  for (int mi = 0; mi < MFR; ++mi) {
#pragma unroll
    for (int r = 0; r < 4; ++r) {
      int gm = bm + wm * (BM / 2) + mi * 16 + r0 + r;
      if (gm >= M) continue;
#pragma unroll
      for (int ni = 0; ni < 2; ++ni) {
        int go = bo + wo * 32 + ni * 16 + l15;
        float vv = acc[mi][ni][r] + bias[go];
        vv = vv > 0.0f ? vv : 0.0f;
        uint32_t a = 0u, b = (uint32_t)(gm * O + go);
        threefry2x32(f0, f1, a, b);
        float res = vv * normal_from_bits(a ^ b);
        out[(size_t)gm * O + go] = res;
        if (outb) outb[(size_t)gm * obstride + go] = f2bf(res);
      }
    }
  }
}

// ---------------- host orchestration ----------------
extern "C" void kernel_launch(void* const* d_in, const int* in_sizes, int n_in,
                              void* d_out, int out_size, void* d_ws, size_t ws_size,
                              hipStream_t stream) {
  const float* v    = (const float*)d_in[0];
  const int*  edges = (const int*)d_in[1];
  const float* W1 = (const float*)d_in[2];
  const float* b1 = (const float*)d_in[3];
  const float* W2 = (const float*)d_in[4];
  const float* b2 = (const float*)d_in[5];
  const float* W3 = (const float*)d_in[6];
  const float* b3 = (const float*)d_in[7];
  float* out = (float*)d_out;

  const int N = in_sizes[0] / 86;
  const int E = in_sizes[1] / 2;
  const int* rows = edges;
  const int* cols = edges + E;

  // ---- ws carve (16B-aligned chunks) ----
  uintptr_t cur = (uintptr_t)d_ws;
  auto alloc = [&](size_t bytes) {
    cur = (cur + 15) & ~(uintptr_t)15;
    void* p = (void*)cur;
    cur += bytes;
    return p;
  };
  float2* ecv          = (float2*)alloc((size_t)E * 8);
  int* counts          = (int*)alloc((size_t)N * 4);
  int* degs            = (int*)alloc((size_t)N * 4);
  int* row_ptr         = (int*)alloc((size_t)(N + 1) * 4);
  int* cursor          = (int*)alloc((size_t)N * 4);
  float* dinv          = (float*)alloc((size_t)N * 4);
  unsigned short* tx1b = (unsigned short*)alloc((size_t)N * 256 * 2);
  unsigned short* tx2b = (unsigned short*)alloc((size_t)N * 256 * 2);
  unsigned short* vb   = (unsigned short*)alloc((size_t)N * 96 * 2);
  unsigned short* x1b  = (unsigned short*)alloc((size_t)N * 128 * 2);
  unsigned short* x2b  = (unsigned short*)alloc((size_t)N * 256 * 2);
  unsigned short* Wt   = (unsigned short*)alloc((size_t)3 * 512 * 256 * 2);

  float* x1 = out;
  float* x2 = x1 + (size_t)N * 128;
  float* x3 = x2 + (size_t)N * 256;

  // CSR build + norm
  hipMemsetAsync(counts, 0, (size_t)2 * N * sizeof(int), stream);
  count_kernel<<<(E + 255) / 256, 256, 0, stream>>>(rows, cols, counts, degs, E);
  dinv_kernel<<<(N + 255) / 256, 256, 0, stream>>>(degs, dinv, N);
  scan_kernel<<<1, SCAN_T, 0, stream>>>(counts, row_ptr, cursor, N);
  fill_kernel<<<(E + 255) / 256, 256, 0, stream>>>(rows, cols, dinv, cursor, ecv, E);
  vconv_kernel<<<(N * 96 + 255) / 256, 256, 0, stream>>>(v, vb, N);

  const int pblocks = (N + 3) / 4;

  // ---- layer 1: F=86 (pad 96), O=128; BM=64 -> 313 blocks ----
  {
    wtrans_kernel<<<(3 * 128 * 96 + 255) / 256, 256, 0, stream>>>(W1, Wt, 86, 96, 128);
    gather_prop<2, 0, 1><<<pblocks, 256, 0, stream>>>(row_ptr, ecv, vb, 96, nullptr, 0, tx1b, N, 86, 96);
    gather_prop<2, 1, 1><<<pblocks, 256, 0, stream>>>(row_ptr, ecv, tx1b, 96, v, 86, tx2b, N, 86, 96);
    dim3 g((N + 63) / 64, 1);
    gemm3_lds<64, 96, 32><<<g, 512, 0, stream>>>(vb, tx1b, tx2b, Wt, b1, N, 128, x1, x1b, 128, 1);
  }
  // ---- layer 2: F=128, O=256; BM=128 -> (157,2) ----
  {
    wtrans_kernel<<<(3 * 256 * 128 + 255) / 256, 256, 0, stream>>>(W2, Wt, 128, 128, 256);
    gather_prop<2, 0, 1><<<pblocks, 256, 0, stream>>>(row_ptr, ecv, x1b, 128, nullptr, 0, tx1b, N, 128, 128);
    gather_prop<2, 1, 1><<<pblocks, 256, 0, stream>>>(row_ptr, ecv, tx1b, 128, x1, 128, tx2b, N, 128, 128);
    dim3 g((N + 127) / 128, 2);
    gemm3_lds<128, 128, 64><<<g, 512, 0, stream>>>(x1b, tx1b, tx2b, Wt, b2, N, 256, x2, x2b, 256, 2);
  }
  // ---- layer 3: F=256, O=512; BM=128 -> (157,4) ----
  {
    wtrans_kernel<<<(3 * 512 * 256 + 255) / 256, 256, 0, stream>>>(W3, Wt, 256, 256, 512);
    gather_prop<4, 0, 1><<<pblocks, 256, 0, stream>>>(row_ptr, ecv, x2b, 256, nullptr, 0, tx1b, N, 256, 256);
    gather_prop<4, 1, 1><<<pblocks, 256, 0, stream>>>(row_ptr, ecv, tx1b, 256, x2, 256, tx2b, N, 256, 256);
    dim3 g((N + 127) / 128, 4);
    gemm3_lds<128, 256, 64><<<g, 512, 0, stream>>>(x2b, tx1b, tx2b, Wt, b3, N, 512, x3, nullptr, 0, 3);
  }
}